// Round 4
// baseline (2430.688 us; speedup 1.0000x reference)
//
#include <hip/hip_runtime.h>
#include <hip/hip_bf16.h>

typedef __hip_bfloat16 bf16;

#define DEVINL __device__ __forceinline__

constexpr int Hh = 8;    // hidden size
constexpr int G3 = 24;   // 3*H gate rows
constexpr int TT = 512;  // timesteps

DEVINL float toF(float x) { return x; }
DEVINL float toF(bf16 x)  { return __bfloat162float(x); }
DEVINL void fromF(float v, float& d) { d = v; }
DEVINL void fromF(float v, bf16& d)  { d = __float2bfloat16(v); }

DEVINL float fast_sigmoid(float x) {
    x = fminf(fmaxf(x, -30.f), 30.f);
    float e = __expf(-x);
    return __builtin_amdgcn_rcpf(1.f + e);
}
DEVINL float fast_tanh(float x) {
    x = fminf(fmaxf(x, -15.f), 15.f);
    float e = __expf(-2.f * x);
    return (1.f - e) * __builtin_amdgcn_rcpf(1.f + e);
}

// One (sequence, direction) unit per 8 lanes. Lane i owns gate rows
// {i, 8+i, 16+i} of the 24x* weight matrices and computes h-component i.
// Full h vector replicated per lane via 8-lane shuffle broadcast per step.
// Input projection fused into the scan (never materializes (N,T,24)).
template <typename InT, typename OutT, int IN_DIM, bool LAST>
__global__ __launch_bounds__(256, 3) void gru_scan(
    const InT* __restrict__ x,           // (n, T, IN_DIM)
    const float* __restrict__ Wih,       // (2, 24, IN_DIM) fp32
    const float* __restrict__ Whh,       // (2, 24, 8)      fp32
    const float* __restrict__ bih,       // (2, 24)
    const float* __restrict__ bhh,       // (2, 24)
    OutT* __restrict__ out,              // (n, T, 16): fwd->[0:8], bwd->[8:16]
    float* __restrict__ last,            // (n, 16) only when LAST
    int n)
{
    const int tid   = threadIdx.x;
    const int lane8 = tid & 7;
    const int unit  = blockIdx.x * 32 + (tid >> 3);
    const int dir   = unit >= n ? 1 : 0;       // blocks are dir-uniform (n % 32 == 0)
    const int seq   = unit - dir * n;

    const int g0 = lane8, g1 = 8 + lane8, g2 = 16 + lane8;

    // ---- weights into registers (amortized over T=512 steps) ----
    const float* Wd = Wih + (size_t)dir * G3 * IN_DIM;
    float wi0[IN_DIM], wi1[IN_DIM], wi2[IN_DIM];
#pragma unroll
    for (int k = 0; k < IN_DIM; ++k) {
        wi0[k] = Wd[g0 * IN_DIM + k];
        wi1[k] = Wd[g1 * IN_DIM + k];
        wi2[k] = Wd[g2 * IN_DIM + k];
    }
    const float* Hd = Whh + (size_t)dir * G3 * Hh;
    float wh0[Hh], wh1[Hh], wh2[Hh];
#pragma unroll
    for (int k = 0; k < Hh; ++k) {
        wh0[k] = Hd[g0 * Hh + k];
        wh1[k] = Hd[g1 * Hh + k];
        wh2[k] = Hd[g2 * Hh + k];
    }
    // r,z gates: fold b_ih + b_hh; n gate: keep separate (hn scaled by r)
    const float br  = bih[dir * G3 + g0] + bhh[dir * G3 + g0];
    const float bz  = bih[dir * G3 + g1] + bhh[dir * G3 + g1];
    const float bxn = bih[dir * G3 + g2];
    const float bhn = bhh[dir * G3 + g2];

    float h[Hh];
#pragma unroll
    for (int k = 0; k < Hh; ++k) h[k] = 0.f;

    const int t0 = dir ? (TT - 1) : 0;
    const InT* xp = x + ((size_t)seq * TT + t0) * IN_DIM
                      + (IN_DIM == 16 ? 2 * lane8 : lane8);
    const long xstep = dir ? -IN_DIM : IN_DIM;
    OutT* op = nullptr;
    long ostep = 0;
    if (!LAST) {
        op = out + ((size_t)seq * TT + t0) * 16 + dir * 8 + lane8;
        ostep = dir ? -16 : 16;
    }
    const int base = tid & 56;   // 8-lane group base within the wave

    // layer-3 backward: only out_b[:, T-1] is ever consumed = its FIRST step
    const int steps = (LAST && dir) ? 1 : TT;

    for (int s = 0; s < steps; ++s) {
        float sr = br, sz = bz, xn = bxn, hn = bhn;

        // cooperative x_t load: lane holds 1 (IN_DIM=8) or 2 (IN_DIM=16) values
        float x0 = toF(xp[0]);
        float x1 = 0.f;
        if (IN_DIM == 16) x1 = toF(xp[1]);
        xp += xstep;

        // input projection: broadcast x_t across the 8-lane group
#pragma unroll
        for (int j = 0; j < 8; ++j) {
            float a = __shfl(x0, base | j, 64);
            if (IN_DIM == 16) {
                float b = __shfl(x1, base | j, 64);
                sr = fmaf(wi0[2 * j], a, sr); sr = fmaf(wi0[2 * j + 1], b, sr);
                sz = fmaf(wi1[2 * j], a, sz); sz = fmaf(wi1[2 * j + 1], b, sz);
                xn = fmaf(wi2[2 * j], a, xn); xn = fmaf(wi2[2 * j + 1], b, xn);
            } else {
                sr = fmaf(wi0[j], a, sr);
                sz = fmaf(wi1[j], a, sz);
                xn = fmaf(wi2[j], a, xn);
            }
        }
        // recurrent projection
#pragma unroll
        for (int j = 0; j < 8; ++j) {
            sr = fmaf(wh0[j], h[j], sr);
            sz = fmaf(wh1[j], h[j], sz);
            hn = fmaf(wh2[j], h[j], hn);
        }
        float r  = fast_sigmoid(sr);
        float z  = fast_sigmoid(sz);
        float nn = fast_tanh(fmaf(r, hn, xn));
        float hnew = fmaf(z, h[lane8] - nn, nn);    // (1-z)*n + z*h

        if (!LAST) { fromF(hnew, *op); op += ostep; }

        // all-gather new h across the 8-lane group
#pragma unroll
        for (int j = 0; j < 8; ++j) h[j] = __shfl(hnew, base | j, 64);
    }

    if (LAST) last[(size_t)seq * 16 + dir * 8 + lane8] = h[lane8];
}

// last (n,16) fp32 -> lin1(16->8) -> LeakyReLU(0.2) -> lin2(8->8) -> fp32 out
__global__ void head_kernel(const float* __restrict__ last,
                            const float* __restrict__ w1, const float* __restrict__ b1,
                            const float* __restrict__ w2, const float* __restrict__ b2,
                            float* __restrict__ out, int n)
{
    int i = blockIdx.x * blockDim.x + threadIdx.x;
    if (i >= n) return;
    const float* v = last + (size_t)i * 16;
    float h1[8];
#pragma unroll
    for (int j = 0; j < 8; ++j) {
        float a = b1[j];
#pragma unroll
        for (int k = 0; k < 16; ++k) a = fmaf(w1[j * 16 + k], v[k], a);
        h1[j] = a >= 0.f ? a : 0.2f * a;
    }
#pragma unroll
    for (int j = 0; j < 8; ++j) {
        float o = b2[j];
#pragma unroll
        for (int k = 0; k < 8; ++k) o = fmaf(w2[j * 8 + k], h1[k], o);
        out[(size_t)i * 8 + j] = o;
    }
}

extern "C" void kernel_launch(void* const* d_in, const int* in_sizes, int n_in,
                              void* d_out, int out_size, void* d_ws, size_t ws_size,
                              hipStream_t stream)
{
    const float* raw  = (const float*)d_in[0];
    const float* Wih0 = (const float*)d_in[1];
    const float* Whh0 = (const float*)d_in[2];
    const float* bih0 = (const float*)d_in[3];
    const float* bhh0 = (const float*)d_in[4];
    const float* WihR = (const float*)d_in[5];
    const float* WhhR = (const float*)d_in[6];
    const float* bihR = (const float*)d_in[7];
    const float* bhhR = (const float*)d_in[8];
    const float* w1   = (const float*)d_in[9];
    const float* b1   = (const float*)d_in[10];
    const float* w2   = (const float*)d_in[11];
    const float* b2   = (const float*)d_in[12];

    const int n = in_sizes[0] / (TT * Hh);        // 12800 sequences
    const size_t bufE = (size_t)n * TT * 16;      // elements per (n,T,16) buffer
    dim3 blk(256);
    dim3 grid((unsigned)((2 * n) / 32));          // 32 units/block, dirs back-to-back
    dim3 hgrid((unsigned)((n + 255) / 256));

    const size_t need_f32 = bufE * 2 * sizeof(float) + (size_t)n * 16 * sizeof(float);

    if (ws_size >= need_f32) {
        // fp32 inter-layer buffers (max accuracy)
        float* bufA  = (float*)d_ws;
        float* bufB  = bufA + bufE;
        float* lastb = bufB + bufE;
        gru_scan<float, float, 8, false><<<grid, blk, 0, stream>>>(
            raw, Wih0, Whh0, bih0, bhh0, bufA, (float*)nullptr, n);
        gru_scan<float, float, 16, false><<<grid, blk, 0, stream>>>(
            bufA, WihR + 0 * 2 * G3 * 16, WhhR + 0 * 2 * G3 * 8,
            bihR + 0 * 2 * G3, bhhR + 0 * 2 * G3, bufB, (float*)nullptr, n);
        gru_scan<float, float, 16, false><<<grid, blk, 0, stream>>>(
            bufB, WihR + 1 * 2 * G3 * 16, WhhR + 1 * 2 * G3 * 8,
            bihR + 1 * 2 * G3, bhhR + 1 * 2 * G3, bufA, (float*)nullptr, n);
        gru_scan<float, float, 16, true><<<grid, blk, 0, stream>>>(
            bufA, WihR + 2 * 2 * G3 * 16, WhhR + 2 * 2 * G3 * 8,
            bihR + 2 * 2 * G3, bhhR + 2 * 2 * G3, (float*)nullptr, lastb, n);
        head_kernel<<<hgrid, blk, 0, stream>>>(
            lastb, w1, b1, w2, b2, (float*)d_out, n);
    } else {
        // bf16 inter-layer buffers (half the workspace + traffic)
        bf16* bufA  = (bf16*)d_ws;
        bf16* bufB  = bufA + bufE;
        float* lastb = (float*)(bufB + bufE);
        gru_scan<float, bf16, 8, false><<<grid, blk, 0, stream>>>(
            raw, Wih0, Whh0, bih0, bhh0, bufA, (float*)nullptr, n);
        gru_scan<bf16, bf16, 16, false><<<grid, blk, 0, stream>>>(
            bufA, WihR + 0 * 2 * G3 * 16, WhhR + 0 * 2 * G3 * 8,
            bihR + 0 * 2 * G3, bhhR + 0 * 2 * G3, bufB, (float*)nullptr, n);
        gru_scan<bf16, bf16, 16, false><<<grid, blk, 0, stream>>>(
            bufB, WihR + 1 * 2 * G3 * 16, WhhR + 1 * 2 * G3 * 8,
            bihR + 1 * 2 * G3, bhhR + 1 * 2 * G3, bufA, (float*)nullptr, n);
        gru_scan<bf16, bf16, 16, true><<<grid, blk, 0, stream>>>(
            bufA, WihR + 2 * 2 * G3 * 16, WhhR + 2 * 2 * G3 * 8,
            bihR + 2 * 2 * G3, bhhR + 2 * 2 * G3, (bf16*)nullptr, lastb, n);
        head_kernel<<<hgrid, blk, 0, stream>>>(
            lastb, w1, b1, w2, b2, (float*)d_out, n);
    }
}

// Round 5
// 1885.739 us; speedup vs baseline: 1.2890x; 1.2890x over previous
//
#include <hip/hip_runtime.h>
#include <hip/hip_bf16.h>
#include <type_traits>

typedef __hip_bfloat16 bf16;

#define DEVINL __device__ __forceinline__

constexpr int Hh = 8;    // hidden size
constexpr int G3 = 24;   // 3*H gate rows
constexpr int TT = 512;  // timesteps

DEVINL float toF(float x) { return x; }
DEVINL float toF(bf16 x)  { return __bfloat162float(x); }
DEVINL void fromF(float v, float& d) { d = v; }
DEVINL void fromF(float v, bf16& d)  { d = __float2bfloat16(v); }

DEVINL float fast_sigmoid(float x) {
    x = fminf(fmaxf(x, -30.f), 30.f);
    float e = __expf(-x);
    return __builtin_amdgcn_rcpf(1.f + e);
}
DEVINL float fast_tanh(float x) {
    x = fminf(fmaxf(x, -15.f), 15.f);
    float e = __expf(-2.f * x);
    return (1.f - e) * __builtin_amdgcn_rcpf(1.f + e);
}

// 8-lane broadcast of lane (group_base | j) via constant-pattern ds_swizzle.
// BitMode: src_lane = (lane & 0x18) | j within each 32-lane half.
template <int J>
DEVINL float bcast8(float v) {
    return __int_as_float(__builtin_amdgcn_ds_swizzle(
        __float_as_int(v), (J << 5) | 0x18));
}

template <typename InT, int IN_DIM>
DEVINL void load_x(float* xv, const InT* p) {
    if constexpr (std::is_same<InT, float>::value) {
        const float4* p4 = (const float4*)p;
#pragma unroll
        for (int q = 0; q < IN_DIM / 4; ++q) {
            float4 v = p4[q];
            xv[4 * q + 0] = v.x; xv[4 * q + 1] = v.y;
            xv[4 * q + 2] = v.z; xv[4 * q + 3] = v.w;
        }
    } else {
#pragma unroll
        for (int k = 0; k < IN_DIM; ++k) xv[k] = toF(p[k]);
    }
}

// One (sequence, direction) unit per 8 lanes. Lane i owns gate rows
// {i, 8+i, 16+i}; all 8 lanes redundantly load the full x_t row (same-address
// lanes coalesce; load is independent of the recurrence -> prefetched 1 step
// ahead). h replicated per lane via 8 constant ds_swizzle broadcasts per step.
template <typename InT, typename OutT, int IN_DIM, bool LAST>
__global__ __launch_bounds__(64, 4) void gru_scan(
    const InT* __restrict__ x,           // (n, T, IN_DIM)
    const float* __restrict__ Wih,       // (2, 24, IN_DIM)
    const float* __restrict__ Whh,       // (2, 24, 8)
    const float* __restrict__ bih,       // (2, 24)
    const float* __restrict__ bhh,       // (2, 24)
    OutT* __restrict__ out,              // (n, T, 16): fwd->[0:8], bwd->[8:16]
    float* __restrict__ last,            // (n, 16) only when LAST
    int n)
{
    const int tid   = threadIdx.x;
    const int lane8 = tid & 7;
    const int unit  = blockIdx.x * 8 + (tid >> 3);
    const int dir   = unit >= n ? 1 : 0;       // blocks are dir-uniform (n % 8 == 0)
    const int seq   = unit - dir * n;

    const int g0 = lane8, g1 = 8 + lane8, g2 = 16 + lane8;

    // ---- weights into registers (amortized over T=512 steps) ----
    const float* Wd = Wih + (size_t)dir * G3 * IN_DIM;
    float wi0[IN_DIM], wi1[IN_DIM], wi2[IN_DIM];
#pragma unroll
    for (int k = 0; k < IN_DIM; ++k) {
        wi0[k] = Wd[g0 * IN_DIM + k];
        wi1[k] = Wd[g1 * IN_DIM + k];
        wi2[k] = Wd[g2 * IN_DIM + k];
    }
    const float* Hd = Whh + (size_t)dir * G3 * Hh;
    float wh0[Hh], wh1[Hh], wh2[Hh];
#pragma unroll
    for (int k = 0; k < Hh; ++k) {
        wh0[k] = Hd[g0 * Hh + k];
        wh1[k] = Hd[g1 * Hh + k];
        wh2[k] = Hd[g2 * Hh + k];
    }
    const float br  = bih[dir * G3 + g0] + bhh[dir * G3 + g0];
    const float bz  = bih[dir * G3 + g1] + bhh[dir * G3 + g1];
    const float bxn = bih[dir * G3 + g2];
    const float bhn = bhh[dir * G3 + g2];

    float h[Hh];
#pragma unroll
    for (int k = 0; k < Hh; ++k) h[k] = 0.f;

    const int t0 = dir ? (TT - 1) : 0;
    const InT* xp = x + ((size_t)seq * TT + t0) * IN_DIM;   // group base, no lane offset
    const long xstep = dir ? -IN_DIM : IN_DIM;
    OutT* op = nullptr;
    long ostep = 0;
    if (!LAST) {
        op = out + ((size_t)seq * TT + t0) * 16 + dir * 8 + lane8;
        ostep = dir ? -16 : 16;
    }

    // layer-3 backward: only out_b[:, T-1] is ever consumed = its FIRST step
    const int steps = (LAST && dir) ? 1 : TT;

    float xv[IN_DIM], xnx[IN_DIM];
    load_x<InT, IN_DIM>(xv, xp);
    xp += xstep;

    for (int s = 0; s < steps; ++s) {
        // ---- input projection from prefetched registers (h-independent) ----
        float sr = br, sz = bz, xn = bxn;
#pragma unroll
        for (int k = 0; k < IN_DIM; ++k) {
            sr = fmaf(wi0[k], xv[k], sr);
            sz = fmaf(wi1[k], xv[k], sz);
            xn = fmaf(wi2[k], xv[k], xn);
        }

        // ---- prefetch next x_t (clamped to a valid address on last step) ----
        const InT* pf = (s + 1 < steps) ? xp : x;
        load_x<InT, IN_DIM>(xnx, pf);
        xp += xstep;

        // ---- recurrent projection ----
        float hn = bhn;
#pragma unroll
        for (int j = 0; j < 8; ++j) {
            sr = fmaf(wh0[j], h[j], sr);
            sz = fmaf(wh1[j], h[j], sz);
            hn = fmaf(wh2[j], h[j], hn);
        }
        float r  = fast_sigmoid(sr);
        float z  = fast_sigmoid(sz);
        float nn = fast_tanh(fmaf(r, hn, xn));
        float hnew = fmaf(z, h[lane8] - nn, nn);    // (1-z)*n + z*h

        if (!LAST) { fromF(hnew, *op); op += ostep; }

        // ---- all-gather new h across the 8-lane group (const-pattern swizzle) ----
        h[0] = bcast8<0>(hnew); h[1] = bcast8<1>(hnew);
        h[2] = bcast8<2>(hnew); h[3] = bcast8<3>(hnew);
        h[4] = bcast8<4>(hnew); h[5] = bcast8<5>(hnew);
        h[6] = bcast8<6>(hnew); h[7] = bcast8<7>(hnew);

#pragma unroll
        for (int k = 0; k < IN_DIM; ++k) xv[k] = xnx[k];
    }

    if (LAST) last[(size_t)seq * 16 + dir * 8 + lane8] = h[lane8];
}

// last (n,16) fp32 -> lin1(16->8) -> LeakyReLU(0.2) -> lin2(8->8) -> fp32 out
__global__ void head_kernel(const float* __restrict__ last,
                            const float* __restrict__ w1, const float* __restrict__ b1,
                            const float* __restrict__ w2, const float* __restrict__ b2,
                            float* __restrict__ out, int n)
{
    int i = blockIdx.x * blockDim.x + threadIdx.x;
    if (i >= n) return;
    const float* v = last + (size_t)i * 16;
    float h1[8];
#pragma unroll
    for (int j = 0; j < 8; ++j) {
        float a = b1[j];
#pragma unroll
        for (int k = 0; k < 16; ++k) a = fmaf(w1[j * 16 + k], v[k], a);
        h1[j] = a >= 0.f ? a : 0.2f * a;
    }
#pragma unroll
    for (int j = 0; j < 8; ++j) {
        float o = b2[j];
#pragma unroll
        for (int k = 0; k < 8; ++k) o = fmaf(w2[j * 8 + k], h1[k], o);
        out[(size_t)i * 8 + j] = o;
    }
}

extern "C" void kernel_launch(void* const* d_in, const int* in_sizes, int n_in,
                              void* d_out, int out_size, void* d_ws, size_t ws_size,
                              hipStream_t stream)
{
    const float* raw  = (const float*)d_in[0];
    const float* Wih0 = (const float*)d_in[1];
    const float* Whh0 = (const float*)d_in[2];
    const float* bih0 = (const float*)d_in[3];
    const float* bhh0 = (const float*)d_in[4];
    const float* WihR = (const float*)d_in[5];
    const float* WhhR = (const float*)d_in[6];
    const float* bihR = (const float*)d_in[7];
    const float* bhhR = (const float*)d_in[8];
    const float* w1   = (const float*)d_in[9];
    const float* b1   = (const float*)d_in[10];
    const float* w2   = (const float*)d_in[11];
    const float* b2   = (const float*)d_in[12];

    const int n = in_sizes[0] / (TT * Hh);        // 12800 sequences
    const size_t bufE = (size_t)n * TT * 16;      // elements per (n,T,16) buffer
    dim3 blk(64);
    dim3 grid((unsigned)((2 * n) / 8));           // 8 units per 64-thread block
    dim3 hblk(256);
    dim3 hgrid((unsigned)((n + 255) / 256));

    const size_t need_f32 = bufE * 2 * sizeof(float) + (size_t)n * 16 * sizeof(float);

    if (ws_size >= need_f32) {
        // fp32 inter-layer buffers (max accuracy)
        float* bufA  = (float*)d_ws;
        float* bufB  = bufA + bufE;
        float* lastb = bufB + bufE;
        gru_scan<float, float, 8, false><<<grid, blk, 0, stream>>>(
            raw, Wih0, Whh0, bih0, bhh0, bufA, (float*)nullptr, n);
        gru_scan<float, float, 16, false><<<grid, blk, 0, stream>>>(
            bufA, WihR + 0 * 2 * G3 * 16, WhhR + 0 * 2 * G3 * 8,
            bihR + 0 * 2 * G3, bhhR + 0 * 2 * G3, bufB, (float*)nullptr, n);
        gru_scan<float, float, 16, false><<<grid, blk, 0, stream>>>(
            bufB, WihR + 1 * 2 * G3 * 16, WhhR + 1 * 2 * G3 * 8,
            bihR + 1 * 2 * G3, bhhR + 1 * 2 * G3, bufA, (float*)nullptr, n);
        gru_scan<float, float, 16, true><<<grid, blk, 0, stream>>>(
            bufA, WihR + 2 * 2 * G3 * 16, WhhR + 2 * 2 * G3 * 8,
            bihR + 2 * 2 * G3, bhhR + 2 * 2 * G3, (float*)nullptr, lastb, n);
        head_kernel<<<hgrid, hblk, 0, stream>>>(
            lastb, w1, b1, w2, b2, (float*)d_out, n);
    } else {
        // bf16 inter-layer buffers (half the workspace + traffic)
        bf16* bufA  = (bf16*)d_ws;
        bf16* bufB  = bufA + bufE;
        float* lastb = (float*)(bufB + bufE);
        gru_scan<float, bf16, 8, false><<<grid, blk, 0, stream>>>(
            raw, Wih0, Whh0, bih0, bhh0, bufA, (float*)nullptr, n);
        gru_scan<bf16, bf16, 16, false><<<grid, blk, 0, stream>>>(
            bufA, WihR + 0 * 2 * G3 * 16, WhhR + 0 * 2 * G3 * 8,
            bihR + 0 * 2 * G3, bhhR + 0 * 2 * G3, bufB, (float*)nullptr, n);
        gru_scan<bf16, bf16, 16, false><<<grid, blk, 0, stream>>>(
            bufB, WihR + 1 * 2 * G3 * 16, WhhR + 1 * 2 * G3 * 8,
            bihR + 1 * 2 * G3, bhhR + 1 * 2 * G3, bufA, (float*)nullptr, n);
        gru_scan<bf16, bf16, 16, true><<<grid, blk, 0, stream>>>(
            bufA, WihR + 2 * 2 * G3 * 16, WhhR + 2 * 2 * G3 * 8,
            bihR + 2 * 2 * G3, bhhR + 2 * 2 * G3, (bf16*)nullptr, lastb, n);
        head_kernel<<<hgrid, hblk, 0, stream>>>(
            lastb, w1, b1, w2, b2, (float*)d_out, n);
    }
}

// Round 6
// 1879.414 us; speedup vs baseline: 1.2933x; 1.0034x over previous
//
#include <hip/hip_runtime.h>
#include <hip/hip_bf16.h>
#include <type_traits>

typedef __hip_bfloat16 bf16;

#define DEVINL __device__ __forceinline__

constexpr int Hh = 8;    // hidden size
constexpr int G3 = 24;   // 3*H gate rows
constexpr int TT = 512;  // timesteps

DEVINL float toF(float x) { return x; }
DEVINL float toF(bf16 x)  { return __bfloat162float(x); }
DEVINL void fromF(float v, float& d) { d = v; }
DEVINL void fromF(float v, bf16& d)  { d = __float2bfloat16(v); }

DEVINL float fast_sigmoid(float x) {
    x = fminf(fmaxf(x, -30.f), 30.f);
    float e = __expf(-x);
    return __builtin_amdgcn_rcpf(1.f + e);
}
DEVINL float fast_tanh(float x) {
    x = fminf(fmaxf(x, -15.f), 15.f);
    float e = __expf(-2.f * x);
    return (1.f - e) * __builtin_amdgcn_rcpf(1.f + e);
}

// 8-lane broadcast of lane (group_base | j) via constant-pattern ds_swizzle.
// BitMode: src_lane = (lane & 0x18) | j within each 32-lane half.
template <int J>
DEVINL float bcast8(float v) {
    return __int_as_float(__builtin_amdgcn_ds_swizzle(
        __float_as_int(v), (J << 5) | 0x18));
}

template <typename InT, int IN_DIM>
DEVINL void load_x(float* xv, const InT* p) {
    if constexpr (std::is_same<InT, float>::value) {
        const float4* p4 = (const float4*)p;
#pragma unroll
        for (int q = 0; q < IN_DIM / 4; ++q) {
            float4 v = p4[q];
            xv[4 * q + 0] = v.x; xv[4 * q + 1] = v.y;
            xv[4 * q + 2] = v.z; xv[4 * q + 3] = v.w;
        }
    } else {
#pragma unroll
        for (int k = 0; k < IN_DIM; ++k) xv[k] = toF(p[k]);
    }
}

// One (sequence, direction) unit per 8 lanes. Lane i owns gate rows
// {i, 8+i, 16+i}; all 8 lanes redundantly load the full x_t row (same-address
// lanes coalesce; load is independent of the recurrence -> prefetched 1 step
// ahead). h replicated per lane via 8 constant ds_swizzle broadcasts per step.
// __launch_bounds__(64,2): 256-VGPR budget so weights stay register-resident.
template <typename InT, typename OutT, int IN_DIM, bool LAST>
__global__ __launch_bounds__(64, 2) void gru_scan(
    const InT* __restrict__ x,           // (n, T, IN_DIM)
    const float* __restrict__ Wih,       // (2, 24, IN_DIM)
    const float* __restrict__ Whh,       // (2, 24, 8)
    const float* __restrict__ bih,       // (2, 24)
    const float* __restrict__ bhh,       // (2, 24)
    OutT* __restrict__ out,              // (n, T, 16): fwd->[0:8], bwd->[8:16]
    float* __restrict__ last,            // (n, 16) only when LAST
    int n)
{
    const int tid   = threadIdx.x;
    const int lane8 = tid & 7;
    const int unit  = blockIdx.x * 8 + (tid >> 3);
    const int dir   = unit >= n ? 1 : 0;       // blocks are dir-uniform (n % 8 == 0)
    const int seq   = unit - dir * n;

    const int g0 = lane8, g1 = 8 + lane8, g2 = 16 + lane8;

    // ---- weights into registers (amortized over T=512 steps) ----
    const float* Wd = Wih + (size_t)dir * G3 * IN_DIM;
    float wi0[IN_DIM], wi1[IN_DIM], wi2[IN_DIM];
#pragma unroll
    for (int k = 0; k < IN_DIM; ++k) {
        wi0[k] = Wd[g0 * IN_DIM + k];
        wi1[k] = Wd[g1 * IN_DIM + k];
        wi2[k] = Wd[g2 * IN_DIM + k];
    }
    const float* Hd = Whh + (size_t)dir * G3 * Hh;
    float wh0[Hh], wh1[Hh], wh2[Hh];
#pragma unroll
    for (int k = 0; k < Hh; ++k) {
        wh0[k] = Hd[g0 * Hh + k];
        wh1[k] = Hd[g1 * Hh + k];
        wh2[k] = Hd[g2 * Hh + k];
    }
    const float br  = bih[dir * G3 + g0] + bhh[dir * G3 + g0];
    const float bz  = bih[dir * G3 + g1] + bhh[dir * G3 + g1];
    const float bxn = bih[dir * G3 + g2];
    const float bhn = bhh[dir * G3 + g2];

    float h[Hh];
#pragma unroll
    for (int k = 0; k < Hh; ++k) h[k] = 0.f;

    const int t0 = dir ? (TT - 1) : 0;
    const InT* xp = x + ((size_t)seq * TT + t0) * IN_DIM;   // group base
    const long xstep = dir ? -IN_DIM : IN_DIM;
    OutT* op = nullptr;
    long ostep = 0;
    if (!LAST) {
        op = out + ((size_t)seq * TT + t0) * 16 + dir * 8 + lane8;
        ostep = dir ? -16 : 16;
    }

    // layer-3 backward: only out_b[:, T-1] is ever consumed = its FIRST step
    const int steps = (LAST && dir) ? 1 : TT;

    float xv[IN_DIM], xnx[IN_DIM];
    load_x<InT, IN_DIM>(xv, xp);
    xp += xstep;

    // main loop: steps-1 iterations with unconditional prefetch; last peeled
#pragma unroll 2
    for (int s = 0; s < steps - 1; ++s) {
        // ---- input projection from prefetched registers (h-independent) ----
        float sr = br, sz = bz, xn = bxn;
#pragma unroll
        for (int k = 0; k < IN_DIM; ++k) {
            sr = fmaf(wi0[k], xv[k], sr);
            sz = fmaf(wi1[k], xv[k], sz);
            xn = fmaf(wi2[k], xv[k], xn);
        }

        // ---- prefetch next x_t (always valid: s+1 < steps) ----
        load_x<InT, IN_DIM>(xnx, xp);
        xp += xstep;

        // ---- recurrent projection ----
        float hn = bhn;
#pragma unroll
        for (int j = 0; j < 8; ++j) {
            sr = fmaf(wh0[j], h[j], sr);
            sz = fmaf(wh1[j], h[j], sz);
            hn = fmaf(wh2[j], h[j], hn);
        }
        float r  = fast_sigmoid(sr);
        float z  = fast_sigmoid(sz);
        float nn = fast_tanh(fmaf(r, hn, xn));
        float hnew = fmaf(z, h[lane8] - nn, nn);    // (1-z)*n + z*h

        if (!LAST) { fromF(hnew, *op); op += ostep; }

        // ---- all-gather new h across the 8-lane group ----
        h[0] = bcast8<0>(hnew); h[1] = bcast8<1>(hnew);
        h[2] = bcast8<2>(hnew); h[3] = bcast8<3>(hnew);
        h[4] = bcast8<4>(hnew); h[5] = bcast8<5>(hnew);
        h[6] = bcast8<6>(hnew); h[7] = bcast8<7>(hnew);

#pragma unroll
        for (int k = 0; k < IN_DIM; ++k) xv[k] = xnx[k];
    }

    // ---- final step (no prefetch) ----
    {
        float sr = br, sz = bz, xn = bxn;
#pragma unroll
        for (int k = 0; k < IN_DIM; ++k) {
            sr = fmaf(wi0[k], xv[k], sr);
            sz = fmaf(wi1[k], xv[k], sz);
            xn = fmaf(wi2[k], xv[k], xn);
        }
        float hn = bhn;
#pragma unroll
        for (int j = 0; j < 8; ++j) {
            sr = fmaf(wh0[j], h[j], sr);
            sz = fmaf(wh1[j], h[j], sz);
            hn = fmaf(wh2[j], h[j], hn);
        }
        float r  = fast_sigmoid(sr);
        float z  = fast_sigmoid(sz);
        float nn = fast_tanh(fmaf(r, hn, xn));
        float hnew = fmaf(z, h[lane8] - nn, nn);

        if (!LAST) { fromF(hnew, *op); }
        else       { last[(size_t)seq * 16 + dir * 8 + lane8] = hnew; }
    }
}

// last (n,16) fp32 -> lin1(16->8) -> LeakyReLU(0.2) -> lin2(8->8) -> fp32 out
__global__ void head_kernel(const float* __restrict__ last,
                            const float* __restrict__ w1, const float* __restrict__ b1,
                            const float* __restrict__ w2, const float* __restrict__ b2,
                            float* __restrict__ out, int n)
{
    int i = blockIdx.x * blockDim.x + threadIdx.x;
    if (i >= n) return;
    const float* v = last + (size_t)i * 16;
    float h1[8];
#pragma unroll
    for (int j = 0; j < 8; ++j) {
        float a = b1[j];
#pragma unroll
        for (int k = 0; k < 16; ++k) a = fmaf(w1[j * 16 + k], v[k], a);
        h1[j] = a >= 0.f ? a : 0.2f * a;
    }
#pragma unroll
    for (int j = 0; j < 8; ++j) {
        float o = b2[j];
#pragma unroll
        for (int k = 0; k < 8; ++k) o = fmaf(w2[j * 8 + k], h1[k], o);
        out[(size_t)i * 8 + j] = o;
    }
}

extern "C" void kernel_launch(void* const* d_in, const int* in_sizes, int n_in,
                              void* d_out, int out_size, void* d_ws, size_t ws_size,
                              hipStream_t stream)
{
    const float* raw  = (const float*)d_in[0];
    const float* Wih0 = (const float*)d_in[1];
    const float* Whh0 = (const float*)d_in[2];
    const float* bih0 = (const float*)d_in[3];
    const float* bhh0 = (const float*)d_in[4];
    const float* WihR = (const float*)d_in[5];
    const float* WhhR = (const float*)d_in[6];
    const float* bihR = (const float*)d_in[7];
    const float* bhhR = (const float*)d_in[8];
    const float* w1   = (const float*)d_in[9];
    const float* b1   = (const float*)d_in[10];
    const float* w2   = (const float*)d_in[11];
    const float* b2   = (const float*)d_in[12];

    const int n = in_sizes[0] / (TT * Hh);        // 12800 sequences
    const size_t bufE = (size_t)n * TT * 16;      // elements per (n,T,16) buffer
    dim3 blk(64);
    dim3 grid((unsigned)((2 * n) / 8));           // 8 units per 64-thread block
    dim3 hblk(256);
    dim3 hgrid((unsigned)((n + 255) / 256));

    const size_t need_f32 = bufE * 2 * sizeof(float) + (size_t)n * 16 * sizeof(float);

    if (ws_size >= need_f32) {
        // fp32 inter-layer buffers (max accuracy)
        float* bufA  = (float*)d_ws;
        float* bufB  = bufA + bufE;
        float* lastb = bufB + bufE;
        gru_scan<float, float, 8, false><<<grid, blk, 0, stream>>>(
            raw, Wih0, Whh0, bih0, bhh0, bufA, (float*)nullptr, n);
        gru_scan<float, float, 16, false><<<grid, blk, 0, stream>>>(
            bufA, WihR + 0 * 2 * G3 * 16, WhhR + 0 * 2 * G3 * 8,
            bihR + 0 * 2 * G3, bhhR + 0 * 2 * G3, bufB, (float*)nullptr, n);
        gru_scan<float, float, 16, false><<<grid, blk, 0, stream>>>(
            bufB, WihR + 1 * 2 * G3 * 16, WhhR + 1 * 2 * G3 * 8,
            bihR + 1 * 2 * G3, bhhR + 1 * 2 * G3, bufA, (float*)nullptr, n);
        gru_scan<float, float, 16, true><<<grid, blk, 0, stream>>>(
            bufA, WihR + 2 * 2 * G3 * 16, WhhR + 2 * 2 * G3 * 8,
            bihR + 2 * 2 * G3, bhhR + 2 * 2 * G3, (float*)nullptr, lastb, n);
        head_kernel<<<hgrid, hblk, 0, stream>>>(
            lastb, w1, b1, w2, b2, (float*)d_out, n);
    } else {
        // bf16 inter-layer buffers (half the workspace + traffic)
        bf16* bufA  = (bf16*)d_ws;
        bf16* bufB  = bufA + bufE;
        float* lastb = (float*)(bufB + bufE);
        gru_scan<float, bf16, 8, false><<<grid, blk, 0, stream>>>(
            raw, Wih0, Whh0, bih0, bhh0, bufA, (float*)nullptr, n);
        gru_scan<bf16, bf16, 16, false><<<grid, blk, 0, stream>>>(
            bufA, WihR + 0 * 2 * G3 * 16, WhhR + 0 * 2 * G3 * 8,
            bihR + 0 * 2 * G3, bhhR + 0 * 2 * G3, bufB, (float*)nullptr, n);
        gru_scan<bf16, bf16, 16, false><<<grid, blk, 0, stream>>>(
            bufB, WihR + 1 * 2 * G3 * 16, WhhR + 1 * 2 * G3 * 8,
            bihR + 1 * 2 * G3, bhhR + 1 * 2 * G3, bufA, (float*)nullptr, n);
        gru_scan<bf16, bf16, 16, true><<<grid, blk, 0, stream>>>(
            bufA, WihR + 2 * 2 * G3 * 16, WhhR + 2 * 2 * G3 * 8,
            bihR + 2 * 2 * G3, bhhR + 2 * 2 * G3, (bf16*)nullptr, lastb, n);
        head_kernel<<<hgrid, hblk, 0, stream>>>(
            lastb, w1, b1, w2, b2, (float*)d_out, n);
    }
}